// Round 22
// baseline (271.338 us; speedup 1.0000x reference)
//
#include <hip/hip_runtime.h>
#include <hip/hip_bf16.h>

typedef __hip_bfloat16 bf16;
typedef __bf16 bf16x8 __attribute__((ext_vector_type(8)));
typedef __bf16 bf16x4 __attribute__((ext_vector_type(4)));
typedef short  s16x4  __attribute__((ext_vector_type(4)));
typedef float  f32x4  __attribute__((ext_vector_type(4)));
typedef float  f32x16 __attribute__((ext_vector_type(16)));
typedef unsigned short ushort_t;
typedef unsigned int   uint_t;

#define NH 16
#define NB 2
#define SS 2048
#define EE 1024
#define DH 64
#define DV 128
#define PJW 6144
#define Q1O 0
#define Q2O 1024
#define K1O 2048
#define K2O 3072
#define VO  4096
#define LAM0 0.7778701f
#define LN_EPS 1e-5f
#define VSTR 68            // Vt row stride (2-way bank aliasing = free)
#define SCLQ 0.18033688f   // 0.125 * log2(e)
#define PSEL_LO 0x05040100u
#define PSEL_HI 0x07060302u

__device__ __forceinline__ void gload_lds16(const bf16* g, bf16* l) {
    __builtin_amdgcn_global_load_lds(
        (const __attribute__((address_space(1))) void*)g,
        (__attribute__((address_space(3))) void*)l, 16, 0, 0);
}

__device__ __forceinline__ void stC(float* p, float v) { *p = v; }
__device__ __forceinline__ void stC(bf16* p, float v) { *p = __float2bfloat16(v); }

// PV MFMA: 32x32x8 bf16 (A/B = 4 bf16). Name differs across ROCm versions.
#if __has_builtin(__builtin_amdgcn_mfma_f32_32x32x8_bf16)
__device__ __forceinline__ f32x16 mfma_pv(uint2 a, uint2 b, f32x16 c) {
    return __builtin_amdgcn_mfma_f32_32x32x8_bf16(
        __builtin_bit_cast(bf16x4, a), __builtin_bit_cast(bf16x4, b), c, 0, 0, 0);
}
#elif __has_builtin(__builtin_amdgcn_mfma_f32_32x32x8bf16_1k)
__device__ __forceinline__ f32x16 mfma_pv(uint2 a, uint2 b, f32x16 c) {
    return __builtin_amdgcn_mfma_f32_32x32x8bf16_1k(
        __builtin_bit_cast(s16x4, a), __builtin_bit_cast(s16x4, b), c, 0, 0, 0);
}
#else
__device__ __forceinline__ f32x16 mfma_pv(uint2 a, uint2 b, f32x16 c) {
    asm volatile("s_nop 1\n\tv_mfma_f32_32x32x8_bf16 %0, %1, %2, %0\n\ts_nop 7"
                 : "+v"(c) : "v"(a), "v"(b));
    return c;
}
#endif

// ---------------- fused prep: 5 weight transposes + x f32->bf16 convert ----------------
// z<4: Wq1/Wq2/Wk1/Wk2 (bx<32); z=4: Wv (bx<64); z=5: xcvt (bx<64, y<32 -> 2048 blks)
__global__ __launch_bounds__(256) void prep(const float* __restrict__ W0,
                                            const float* __restrict__ W1,
                                            const float* __restrict__ W2,
                                            const float* __restrict__ W3,
                                            const float* __restrict__ W4,
                                            const float* __restrict__ x,
                                            bf16* __restrict__ WT,
                                            bf16* __restrict__ xb) {
    const int z = blockIdx.z;
    const int bx = blockIdx.x;
    if (z == 5) {   // x convert: 2048 blocks x 256 thr x 8 elems = 4M elems
        const int i = (blockIdx.y * 64 + bx) * 256 + threadIdx.x;
        const float4* p = reinterpret_cast<const float4*>(x) + (size_t)i * 2;
        float4 a = p[0], bq = p[1];
        float f[8] = {a.x, a.y, a.z, a.w, bq.x, bq.y, bq.z, bq.w};
        ushort_t u[8];
#pragma unroll
        for (int j = 0; j < 8; ++j) {
            bf16 h = __float2bfloat16(f[j]);
            u[j] = *reinterpret_cast<ushort_t*>(&h);
        }
        uint4 o;
        o.x = (uint_t)u[0] | ((uint_t)u[1] << 16);
        o.y = (uint_t)u[2] | ((uint_t)u[3] << 16);
        o.z = (uint_t)u[4] | ((uint_t)u[5] << 16);
        o.w = (uint_t)u[6] | ((uint_t)u[7] << 16);
        *(reinterpret_cast<uint4*>(xb) + i) = o;
        return;
    }
    __shared__ float Ts[32][33];
    if (z < 4 && bx >= 32) return;
    const float* W = (z == 0) ? W0 : (z == 1) ? W1 : (z == 2) ? W2 : (z == 3) ? W3 : W4;
    const int N = (z == 4) ? 2048 : 1024;
    const int noff = z * 1024;
    const float scl = (z < 2) ? SCLQ : 1.0f;
    int n0 = bx * 32, k0 = blockIdx.y * 32;
    int t = threadIdx.x, tx = t & 31, ty = t >> 5;
#pragma unroll
    for (int p = 0; p < 4; ++p)
        Ts[ty + 8 * p][tx] = W[(size_t)(k0 + ty + 8 * p) * N + n0 + tx];
    __syncthreads();
#pragma unroll
    for (int p = 0; p < 4; ++p)
        WT[(size_t)(noff + n0 + ty + 8 * p) * 1024 + k0 + tx] =
            __float2bfloat16(Ts[tx][ty + 8 * p] * scl);
}

// ---------------- transpose-convert (Wo) ----------------
__global__ __launch_bounds__(256) void transp(const float* __restrict__ W,
                                              bf16* __restrict__ WT,
                                              int K, int N, int KST, int noff,
                                              float scl) {
    __shared__ float Ts[32][33];
    int n0 = blockIdx.x * 32, k0 = blockIdx.y * 32;
    int t = threadIdx.x, tx = t & 31, ty = t >> 5;
#pragma unroll
    for (int p = 0; p < 4; ++p)
        Ts[ty + 8 * p][tx] = W[(size_t)(k0 + ty + 8 * p) * N + n0 + tx];
    __syncthreads();
#pragma unroll
    for (int p = 0; p < 4; ++p)
        WT[(size_t)(noff + n0 + ty + 8 * p) * KST + k0 + tx] =
            __float2bfloat16(Ts[tx][ty + 8 * p] * scl);
}

// ---------------- MFMA GEMM (bf16 A via global_load_lds; verified R10/R21) ----------------
template<typename CT>
__global__ __launch_bounds__(256) void mgemm(const bf16* __restrict__ A,
                                             const bf16* __restrict__ Bt,
                                             CT* __restrict__ C,
                                             int M, int N, int K) {
    __shared__ bf16 Ahi[128][32];
    __shared__ bf16 Bs[128][32];

    const int t = threadIdx.x;
    const int w = t >> 6, l = t & 63;
    const int c = l & 15, g = l >> 4;
    const int wr = w >> 1, wc = w & 1;

    const int nwg = gridDim.x, cpx = nwg >> 3;
    const int sw = (blockIdx.x & 7) * cpx + (blockIdx.x >> 3);
    const int nbx = N >> 7;
    const int bx = sw % nbx, by = sw / nbx;
    const int row0 = by * 128, col0 = bx * 128;

    f32x4 acc[4][4];
    const f32x4 fz = {0.f, 0.f, 0.f, 0.f};
#pragma unroll
    for (int m = 0; m < 4; ++m)
#pragma unroll
        for (int n = 0; n < 4; ++n) acc[m][n] = fz;

    for (int k0 = 0; k0 < K; k0 += 32) {
        __syncthreads();
#pragma unroll
        for (int i = 0; i < 2; ++i) {
            int r = i * 64 + w * 16 + (l >> 2);
            gload_lds16(&Bt[(size_t)(col0 + r) * K + k0 + (l & 3) * 8],
                        &Bs[0][0] + (size_t)(i * 4 + w) * 512 + l * 8);
            gload_lds16(&A[(size_t)(row0 + r) * K + k0 + (l & 3) * 8],
                        &Ahi[0][0] + (size_t)(i * 4 + w) * 512 + l * 8);
        }
        __syncthreads();

        bf16x8 af[4], bfr[4];
#pragma unroll
        for (int m = 0; m < 4; ++m)
            af[m] = *reinterpret_cast<const bf16x8*>(&Ahi[wr * 64 + m * 16 + c][g * 8]);
#pragma unroll
        for (int n = 0; n < 4; ++n)
            bfr[n] = *reinterpret_cast<const bf16x8*>(&Bs[wc * 64 + n * 16 + c][g * 8]);
#pragma unroll
        for (int m = 0; m < 4; ++m)
#pragma unroll
            for (int n = 0; n < 4; ++n)
                acc[m][n] = __builtin_amdgcn_mfma_f32_16x16x32_bf16(af[m], bfr[n], acc[m][n], 0, 0, 0);
    }

#pragma unroll
    for (int m = 0; m < 4; ++m)
#pragma unroll
        for (int n = 0; n < 4; ++n)
#pragma unroll
            for (int r = 0; r < 4; ++r) {
                int row = row0 + wr * 64 + m * 16 + g * 4 + r;
                int col = col0 + wc * 64 + n * 16 + c;
                stC(&C[(size_t)row * N + col], acc[m][n][r]);
            }
}

// ---------------- swapped 32x32 differential attention, STREAM-SPLIT waves ----------------
// R22 attn = R19/R21 structure; ONLY change: __launch_bounds__(256, 3) -> allow
// 3 blocks/CU (LDS 50.2KB*3 = 150.6 <= 160KB; VGPR 96 well under the cap).
__global__ __launch_bounds__(256, 3) void attn_mfma(
        const bf16* __restrict__ cp,
        const float* __restrict__ lq1, const float* __restrict__ lk1,
        const float* __restrict__ lq2, const float* __restrict__ lk2,
        bf16* __restrict__ merged) {
    __shared__ ushort_t K1s[2][64][64];
    __shared__ ushort_t K2s[2][64][64];
    __shared__ ushort_t Vt[DV][VSTR];

    const int t = threadIdx.x;
    const int w = t >> 6, l = t & 63;
    const int lane = l & 31, h2 = l >> 5;
    const int qgrp = w >> 1, strm = w & 1;

    const int bid = blockIdx.x;
    const int qt  = 31 - (bid >> 5);          // qt-descending
    const int bh  = bid & 31;
    const int h   = bh & (NH - 1), b = bh >> 4;
    const int q0  = qt * 64;
    const int qw0 = q0 + 32 * qgrp;
    const int qg  = qw0 + lane;
    const int ntiles = qt + 1;

    float lam;
    {
        float s1 = lq1[h * DH + l] * lk1[h * DH + l];
        float s2 = lq2[h * DH + l] * lk2[h * DH + l];
#pragma unroll
        for (int m = 32; m >= 1; m >>= 1) {
            s1 += __shfl_xor(s1, m, 64);
            s2 += __shfl_xor(s2, m, 64);
        }
        lam = __expf(s1) - __expf(s2) + LAM0;
    }

    // Q fragments for OWN stream only (B-operand; k = 16*kk + 8*h2 + j)
    bf16x8 qf[4];
    {
        const int QO = strm ? Q2O : Q1O;
        size_t qrow = (size_t)(b * SS + qg) * PJW + h * DH;
#pragma unroll
        for (int kk = 0; kk < 4; ++kk)
            qf[kk] = *reinterpret_cast<const bf16x8*>(&cp[qrow + QO + 16 * kk + 8 * h2]);
    }

    // ---- staging (hoisted pointers) ----
    const size_t TSTEP = (size_t)64 * PJW;
    const int u0 = t, u1 = 256 + t;
    const int r0u = u0 >> 3, jj0 = (u0 & 7) ^ (r0u & 7);
    const int r1u = u1 >> 3, jj1 = (u1 & 7) ^ (r1u & 7);
    const bf16* k1p0 = cp + (size_t)(b * SS + r0u) * PJW + h * DH + jj0 * 8 + K1O;
    const bf16* k1p1 = cp + (size_t)(b * SS + r1u) * PJW + h * DH + jj1 * 8 + K1O;
    const bf16* k2p0 = k1p0 + (K2O - K1O);
    const bf16* k2p1 = k1p1 + (K2O - K1O);
    auto stageK = [&](int buf) {
        bf16* d1 = (bf16*)&K1s[buf][0][0];
        bf16* d2 = (bf16*)&K2s[buf][0][0];
        gload_lds16(k1p0, d1 + u0 * 8);
        gload_lds16(k1p1, d1 + u1 * 8);
        gload_lds16(k2p0, d2 + u0 * 8);
        gload_lds16(k2p1, d2 + u1 * 8);
        k1p0 += TSTEP; k1p1 += TSTEP; k2p0 += TSTEP; k2p1 += TSTEP;
    };
    uint4 va[4];
    const int vk4 = (t & 15) * 4, vc8 = (t >> 4) * 8;
    const bf16* vp0 = cp + (size_t)(b * SS + vk4 + 0) * PJW + VO + h * DV + vc8;
    const bf16* vp1 = cp + (size_t)(b * SS + vk4 + 1) * PJW + VO + h * DV + vc8;
    const bf16* vp2 = cp + (size_t)(b * SS + vk4 + 2) * PJW + VO + h * DV + vc8;
    const bf16* vp3 = cp + (size_t)(b * SS + vk4 + 3) * PJW + VO + h * DV + vc8;
    auto loadV = [&]() {
        va[0] = *reinterpret_cast<const uint4*>(vp0);
        va[1] = *reinterpret_cast<const uint4*>(vp1);
        va[2] = *reinterpret_cast<const uint4*>(vp2);
        va[3] = *reinterpret_cast<const uint4*>(vp3);
        vp0 += TSTEP; vp1 += TSTEP; vp2 += TSTEP; vp3 += TSTEP;
    };

    f32x16 acc[4];
    const f32x16 fz16 = {0.f,0.f,0.f,0.f,0.f,0.f,0.f,0.f,0.f,0.f,0.f,0.f,0.f,0.f,0.f,0.f};
#pragma unroll
    for (int i = 0; i < 4; ++i) acc[i] = fz16;
    float mm = -1e30f, lsum = 0.f;

    // prologue
    stageK(0);
    loadV();

    for (int kt = 0; kt < ntiles; ++kt) {
        const int cur = kt & 1;
        const int k0 = kt * 64;
        const bool diag = (kt + 1 == ntiles);
        const bool skipHi = diag && (qgrp == 0);   // keys 32..63 fully masked

        __syncthreads();                    // A: prev reads done; K DMA + va landed
        if (kt + 1 < ntiles) stageK(cur ^ 1);
        {   // Vt transpose-pack via v_perm (1 op per packed word)
            const uint_t* w0 = reinterpret_cast<const uint_t*>(&va[0]);
            const uint_t* w1 = reinterpret_cast<const uint_t*>(&va[1]);
            const uint_t* w2 = reinterpret_cast<const uint_t*>(&va[2]);
            const uint_t* w3 = reinterpret_cast<const uint_t*>(&va[3]);
#pragma unroll
            for (int j = 0; j < 8; ++j) {
                const int jw = j >> 1;
                const uint_t sel = (j & 1) ? PSEL_HI : PSEL_LO;
                uint2 pk;
                pk.x = __builtin_amdgcn_perm(w1[jw], w0[jw], sel);
                pk.y = __builtin_amdgcn_perm(w3[jw], w2[jw], sel);
                *reinterpret_cast<uint2*>(&Vt[vc8 + j][vk4]) = pk;
            }
        }
        if (kt + 1 < ntiles) loadV();

        // B: Vt + K visible; prefetches stay in flight
        asm volatile("s_waitcnt lgkmcnt(0)" ::: "memory");
        __builtin_amdgcn_sched_barrier(0);
        __builtin_amdgcn_s_barrier();
        __builtin_amdgcn_sched_barrier(0);

        const ushort_t (*Ks)[64] = strm ? K2s[cur] : K1s[cur];

        // ---- QK^T (own stream): lane owns one q, 32 keys in-register ----
        f32x16 sA = fz16, sB = fz16;
        __builtin_amdgcn_s_setprio(1);
#pragma unroll
        for (int kk = 0; kk < 4; ++kk) {
            const int un = ((2 * kk + h2) ^ (lane & 7)) * 8;
            bf16x8 a0 = *reinterpret_cast<const bf16x8*>(&Ks[lane][un]);
            sA = __builtin_amdgcn_mfma_f32_32x32x16_bf16(a0, qf[kk], sA, 0, 0, 0);
        }
        if (!skipHi) {
#pragma unroll
            for (int kk = 0; kk < 4; ++kk) {
                const int un = ((2 * kk + h2) ^ (lane & 7)) * 8;
                bf16x8 a1 = *reinterpret_cast<const bf16x8*>(&Ks[32 + lane][un]);
                sB = __builtin_amdgcn_mfma_f32_32x32x16_bf16(a1, qf[kk], sB, 0, 0, 0);
            }
        }
        __builtin_amdgcn_s_setprio(0);

        float sv[32];
#pragma unroll
        for (int i = 0; i < 16; ++i) { sv[i] = sA[i]; sv[16 + i] = sB[i]; }
        if (diag) {
#pragma unroll
            for (int sb = 0; sb < 2; ++sb)
#pragma unroll
                for (int r = 0; r < 16; ++r) {
                    int key = k0 + 32 * sb + (r & 3) + 8 * (r >> 2) + 4 * h2;
                    if (key > qg) sv[16 * sb + r] = -1e30f;
                }
        }
        // max3-structured tree max over 32 + one cross-half exchange
        float tA[11];
#pragma unroll
        for (int i = 0; i < 10; ++i)
            tA[i] = fmaxf(fmaxf(sv[3 * i], sv[3 * i + 1]), sv[3 * i + 2]);
        tA[10] = fmaxf(sv[30], sv[31]);
        float u0m = fmaxf(fmaxf(tA[0], tA[1]), tA[2]);
        float u1m = fmaxf(fmaxf(tA[3], tA[4]), tA[5]);
        float u2m = fmaxf(fmaxf(tA[6], tA[7]), tA[8]);
        float u3m = fmaxf(tA[9], tA[10]);
        float mt = fmaxf(fmaxf(fmaxf(u0m, u1m), u2m), u3m);
        mt = fmaxf(mt, __shfl_xor(mt, 32, 64));

        float f = 1.f;
        if (!__all(mt - mm <= 8.f)) {
            float mn = fmaxf(mm, mt);
            f = exp2f(mm - mn); mm = mn;
#pragma unroll
            for (int vb = 0; vb < 4; ++vb)
#pragma unroll
                for (int i = 0; i < 16; ++i) acc[vb][i] *= f;
        }

        float rs = 0.f;
        uint2 pa[8];
#pragma unroll
        for (int kc = 0; kc < 4; ++kc) {
            const int base = 4 * kc;          // keys subblock 0
            float p0 = exp2f(sv[base + 0] - mm);
            float p1 = exp2f(sv[base + 1] - mm);
            float p2 = exp2f(sv[base + 2] - mm);
            float p3 = exp2f(sv[base + 3] - mm);
            rs += (p0 + p1) + (p2 + p3);
            bf16 b0 = __float2bfloat16(p0), b1 = __float2bfloat16(p1);
            bf16 b2 = __float2bfloat16(p2), b3 = __float2bfloat16(p3);
            pa[kc].x = (uint_t)(*reinterpret_cast<ushort_t*>(&b0))
                     | ((uint_t)(*reinterpret_cast<ushort_t*>(&b1)) << 16);
            pa[kc].y = (uint_t)(*reinterpret_cast<ushort_t*>(&b2))
                     | ((uint_t)(*reinterpret_cast<ushort_t*>(&b3)) << 16);
        }
        if (!skipHi) {
#pragma unroll
            for (int kc = 4; kc < 8; ++kc) {
                const int base = 16 + 4 * (kc & 3);   // keys subblock 1
                float p0 = exp2f(sv[base + 0] - mm);
                float p1 = exp2f(sv[base + 1] - mm);
                float p2 = exp2f(sv[base + 2] - mm);
                float p3 = exp2f(sv[base + 3] - mm);
                rs += (p0 + p1) + (p2 + p3);
                bf16 b0 = __float2bfloat16(p0), b1 = __float2bfloat16(p1);
                bf16 b2 = __float2bfloat16(p2), b3 = __float2bfloat16(p3);
                pa[kc].x = (uint_t)(*reinterpret_cast<ushort_t*>(&b0))
                         | ((uint_t)(*reinterpret_cast<ushort_t*>(&b1)) << 16);
                pa[kc].y = (uint_t)(*reinterpret_cast<ushort_t*>(&b2))
                         | ((uint_t)(*reinterpret_cast<ushort_t*>(&b3)) << 16);
            }
        }
        lsum = lsum * f + rs;

        __builtin_amdgcn_s_setprio(1);
#pragma unroll
        for (int vb = 0; vb < 4; ++vb)
#pragma unroll
            for (int kc = 0; kc < 4; ++kc) {
                uint2 vf = *reinterpret_cast<const uint2*>(&Vt[32 * vb + lane][8 * kc + 4 * h2]);
                acc[vb] = mfma_pv(vf, pa[kc], acc[vb]);
            }
        if (!skipHi) {
#pragma unroll
            for (int vb = 0; vb < 4; ++vb)
#pragma unroll
                for (int kc = 4; kc < 8; ++kc) {
                    uint2 vf = *reinterpret_cast<const uint2*>(&Vt[32 * vb + lane][8 * kc + 4 * h2]);
                    acc[vb] = mfma_pv(vf, pa[kc], acc[vb]);
                }
        }
        __builtin_amdgcn_s_setprio(0);
    }

    // ---- epilogue: stream exchange + combine + LN + store ----
    lsum += __shfl_xor(lsum, 32, 64);
    const float rl = __builtin_amdgcn_rcpf(lsum);

    float (*ex)[33] = reinterpret_cast<float(*)[33]>(
        qgrp ? (void*)&K2s[0][0][0] : (void*)&K1s[0][0][0]);

    __syncthreads();                        // all loop-phase LDS reads done
#pragma unroll
    for (int half = 0; half < 2; ++half) {
        if (strm) {
#pragma unroll
            for (int vv = 0; vv < 2; ++vv)
#pragma unroll
                for (int i = 0; i < 16; ++i)
                    ex[l][16 * vv + i] = acc[2 * half + vv][i] * rl;
        }
        __syncthreads();
        if (!strm) {
#pragma unroll
            for (int vv = 0; vv < 2; ++vv)
#pragma unroll
                for (int i = 0; i < 16; ++i)
                    acc[2 * half + vv][i] =
                        acc[2 * half + vv][i] * rl - lam * ex[l][16 * vv + i];
        }
        __syncthreads();
    }

    if (!strm) {
        float sum = 0.f;
#pragma unroll
        for (int vb = 0; vb < 4; ++vb)
#pragma unroll
            for (int i = 0; i < 16; ++i) sum += acc[vb][i];
        sum += __shfl_xor(sum, 32, 64);
        const float mu = sum * (1.f / 128.f);
        float var = 0.f;
#pragma unroll
        for (int vb = 0; vb < 4; ++vb)
#pragma unroll
            for (int i = 0; i < 16; ++i) {
                float d = acc[vb][i] - mu;
                var += d * d;
            }
        var += __shfl_xor(var, 32, 64);
        const float scl = rsqrtf(var * (1.f / 128.f) + LN_EPS) * (1.f - LAM0);

        const size_t orow = (size_t)(b * SS + qg) * (2 * EE) + h * DV;
#pragma unroll
        for (int vb = 0; vb < 4; ++vb)
#pragma unroll
            for (int rq = 0; rq < 4; ++rq) {
                bf16 o0 = __float2bfloat16((acc[vb][4 * rq + 0] - mu) * scl);
                bf16 o1 = __float2bfloat16((acc[vb][4 * rq + 1] - mu) * scl);
                bf16 o2 = __float2bfloat16((acc[vb][4 * rq + 2] - mu) * scl);
                bf16 o3 = __float2bfloat16((acc[vb][4 * rq + 3] - mu) * scl);
                uint2 pk;
                pk.x = (uint_t)(*reinterpret_cast<ushort_t*>(&o0))
                     | ((uint_t)(*reinterpret_cast<ushort_t*>(&o1)) << 16);
                pk.y = (uint_t)(*reinterpret_cast<ushort_t*>(&o2))
                     | ((uint_t)(*reinterpret_cast<ushort_t*>(&o3)) << 16);
                *reinterpret_cast<uint2*>(&merged[orow + 32 * vb + 8 * rq + 4 * h2]) = pk;
            }
    }
}

// ---------------- launch ----------------
extern "C" void kernel_launch(void* const* d_in, const int* in_sizes, int n_in,
                              void* d_out, int out_size, void* d_ws, size_t ws_size,
                              hipStream_t stream) {
    (void)in_sizes; (void)n_in; (void)out_size; (void)ws_size;
    const float* x   = (const float*)d_in[0];
    const float* Wq1 = (const float*)d_in[1];
    const float* Wq2 = (const float*)d_in[2];
    const float* Wk1 = (const float*)d_in[3];
    const float* Wk2 = (const float*)d_in[4];
    const float* Wv  = (const float*)d_in[5];
    const float* Wo  = (const float*)d_in[6];
    const float* lq1 = (const float*)d_in[7];
    const float* lk1 = (const float*)d_in[8];
    const float* lq2 = (const float*)d_in[9];
    const float* lk2 = (const float*)d_in[10];
    float* out = (float*)d_out;

    char* ws = (char*)d_ws;
    const size_t MB = 1ull << 20;
    bf16* wcT = (bf16*)(ws);                 // [0,12M)
    bf16* cpj = (bf16*)(ws + 16 * MB);       // [16M,64M)
    bf16* mg  = (bf16*)(ws);                 // [0,16M)  (after proj, wcT dead)
    bf16* woT = (bf16*)(ws + 16 * MB);       // [16M,20M) (after attn, cpj dead)
    bf16* xb  = (bf16*)d_out;                // x-bf16 scratch (overwritten by final GEMM)

    dim3 blk(256);
    // fused prep: 5 weight transposes + x convert in one launch
    prep<<<dim3(64, 32, 6), blk, 0, stream>>>(Wq1, Wq2, Wk1, Wk2, Wv, x, wcT, xb);
    mgemm<bf16><<<dim3((6144 / 128) * (4096 / 128)), blk, 0, stream>>>(
        xb, wcT, cpj, 4096, 6144, 1024);
    attn_mfma<<<dim3(NB * NH * (SS / 64)), blk, 0, stream>>>(
        cpj, lq1, lk1, lq2, lk2, mg);
    transp<<<dim3(32, 64), blk, 0, stream>>>(Wo, woT, 2048, 1024, 2048, 0, 1.0f);
    mgemm<float><<<dim3((1024 / 128) * (4096 / 128)), blk, 0, stream>>>(
        mg, woT, out, 4096, 1024, 2048);
}

// Round 23
// 237.471 us; speedup vs baseline: 1.1426x; 1.1426x over previous
//
#include <hip/hip_runtime.h>
#include <hip/hip_bf16.h>

typedef __hip_bfloat16 bf16;
typedef __bf16 bf16x8 __attribute__((ext_vector_type(8)));
typedef __bf16 bf16x4 __attribute__((ext_vector_type(4)));
typedef short  s16x4  __attribute__((ext_vector_type(4)));
typedef float  f32x4  __attribute__((ext_vector_type(4)));
typedef float  f32x16 __attribute__((ext_vector_type(16)));
typedef unsigned short ushort_t;
typedef unsigned int   uint_t;

#define NH 16
#define NB 2
#define SS 2048
#define EE 1024
#define DH 64
#define DV 128
#define PJW 6144
#define Q1O 0
#define Q2O 1024
#define K1O 2048
#define K2O 3072
#define VO  4096
#define LAM0 0.7778701f
#define LN_EPS 1e-5f
#define VSTR 68            // Vt row stride (2-way bank aliasing = free)
#define SCLQ 0.18033688f   // 0.125 * log2(e)
#define PSEL_LO 0x05040100u
#define PSEL_HI 0x07060302u

__device__ __forceinline__ void gload_lds16(const bf16* g, bf16* l) {
    __builtin_amdgcn_global_load_lds(
        (const __attribute__((address_space(1))) void*)g,
        (__attribute__((address_space(3))) void*)l, 16, 0, 0);
}

__device__ __forceinline__ void stC(float* p, float v) { *p = v; }
__device__ __forceinline__ void stC(bf16* p, float v) { *p = __float2bfloat16(v); }

// PV MFMA: 32x32x8 bf16 (A/B = 4 bf16). Name differs across ROCm versions.
#if __has_builtin(__builtin_amdgcn_mfma_f32_32x32x8_bf16)
__device__ __forceinline__ f32x16 mfma_pv(uint2 a, uint2 b, f32x16 c) {
    return __builtin_amdgcn_mfma_f32_32x32x8_bf16(
        __builtin_bit_cast(bf16x4, a), __builtin_bit_cast(bf16x4, b), c, 0, 0, 0);
}
#elif __has_builtin(__builtin_amdgcn_mfma_f32_32x32x8bf16_1k)
__device__ __forceinline__ f32x16 mfma_pv(uint2 a, uint2 b, f32x16 c) {
    return __builtin_amdgcn_mfma_f32_32x32x8bf16_1k(
        __builtin_bit_cast(s16x4, a), __builtin_bit_cast(s16x4, b), c, 0, 0, 0);
}
#else
__device__ __forceinline__ f32x16 mfma_pv(uint2 a, uint2 b, f32x16 c) {
    asm volatile("s_nop 1\n\tv_mfma_f32_32x32x8_bf16 %0, %1, %2, %0\n\ts_nop 7"
                 : "+v"(c) : "v"(a), "v"(b));
    return c;
}
#endif

// ---------------- fused prep: 5 weight transposes + x f32->bf16 convert ----------------
__global__ __launch_bounds__(256) void prep(const float* __restrict__ W0,
                                            const float* __restrict__ W1,
                                            const float* __restrict__ W2,
                                            const float* __restrict__ W3,
                                            const float* __restrict__ W4,
                                            const float* __restrict__ x,
                                            bf16* __restrict__ WT,
                                            bf16* __restrict__ xb) {
    const int z = blockIdx.z;
    const int bx = blockIdx.x;
    if (z == 5) {   // x convert: 2048 blocks x 256 thr x 8 elems = 4M elems
        const int i = (blockIdx.y * 64 + bx) * 256 + threadIdx.x;
        const float4* p = reinterpret_cast<const float4*>(x) + (size_t)i * 2;
        float4 a = p[0], bq = p[1];
        float f[8] = {a.x, a.y, a.z, a.w, bq.x, bq.y, bq.z, bq.w};
        ushort_t u[8];
#pragma unroll
        for (int j = 0; j < 8; ++j) {
            bf16 h = __float2bfloat16(f[j]);
            u[j] = *reinterpret_cast<ushort_t*>(&h);
        }
        uint4 o;
        o.x = (uint_t)u[0] | ((uint_t)u[1] << 16);
        o.y = (uint_t)u[2] | ((uint_t)u[3] << 16);
        o.z = (uint_t)u[4] | ((uint_t)u[5] << 16);
        o.w = (uint_t)u[6] | ((uint_t)u[7] << 16);
        *(reinterpret_cast<uint4*>(xb) + i) = o;
        return;
    }
    __shared__ float Ts[32][33];
    if (z < 4 && bx >= 32) return;
    const float* W = (z == 0) ? W0 : (z == 1) ? W1 : (z == 2) ? W2 : (z == 3) ? W3 : W4;
    const int N = (z == 4) ? 2048 : 1024;
    const int noff = z * 1024;
    const float scl = (z < 2) ? SCLQ : 1.0f;
    int n0 = bx * 32, k0 = blockIdx.y * 32;
    int t = threadIdx.x, tx = t & 31, ty = t >> 5;
#pragma unroll
    for (int p = 0; p < 4; ++p)
        Ts[ty + 8 * p][tx] = W[(size_t)(k0 + ty + 8 * p) * N + n0 + tx];
    __syncthreads();
#pragma unroll
    for (int p = 0; p < 4; ++p)
        WT[(size_t)(noff + n0 + ty + 8 * p) * 1024 + k0 + tx] =
            __float2bfloat16(Ts[tx][ty + 8 * p] * scl);
}

// ---------------- transpose-convert (Wo) ----------------
__global__ __launch_bounds__(256) void transp(const float* __restrict__ W,
                                              bf16* __restrict__ WT,
                                              int K, int N, int KST, int noff,
                                              float scl) {
    __shared__ float Ts[32][33];
    int n0 = blockIdx.x * 32, k0 = blockIdx.y * 32;
    int t = threadIdx.x, tx = t & 31, ty = t >> 5;
#pragma unroll
    for (int p = 0; p < 4; ++p)
        Ts[ty + 8 * p][tx] = W[(size_t)(k0 + ty + 8 * p) * N + n0 + tx];
    __syncthreads();
#pragma unroll
    for (int p = 0; p < 4; ++p)
        WT[(size_t)(noff + n0 + ty + 8 * p) * KST + k0 + tx] =
            __float2bfloat16(Ts[tx][ty + 8 * p] * scl);
}

// ---------------- MFMA GEMM (bf16 A via global_load_lds; verified R10/R21) ----------------
template<typename CT>
__global__ __launch_bounds__(256) void mgemm(const bf16* __restrict__ A,
                                             const bf16* __restrict__ Bt,
                                             CT* __restrict__ C,
                                             int M, int N, int K) {
    __shared__ bf16 Ahi[128][32];
    __shared__ bf16 Bs[128][32];

    const int t = threadIdx.x;
    const int w = t >> 6, l = t & 63;
    const int c = l & 15, g = l >> 4;
    const int wr = w >> 1, wc = w & 1;

    const int nwg = gridDim.x, cpx = nwg >> 3;
    const int sw = (blockIdx.x & 7) * cpx + (blockIdx.x >> 3);
    const int nbx = N >> 7;
    const int bx = sw % nbx, by = sw / nbx;
    const int row0 = by * 128, col0 = bx * 128;

    f32x4 acc[4][4];
    const f32x4 fz = {0.f, 0.f, 0.f, 0.f};
#pragma unroll
    for (int m = 0; m < 4; ++m)
#pragma unroll
        for (int n = 0; n < 4; ++n) acc[m][n] = fz;

    for (int k0 = 0; k0 < K; k0 += 32) {
        __syncthreads();
#pragma unroll
        for (int i = 0; i < 2; ++i) {
            int r = i * 64 + w * 16 + (l >> 2);
            gload_lds16(&Bt[(size_t)(col0 + r) * K + k0 + (l & 3) * 8],
                        &Bs[0][0] + (size_t)(i * 4 + w) * 512 + l * 8);
            gload_lds16(&A[(size_t)(row0 + r) * K + k0 + (l & 3) * 8],
                        &Ahi[0][0] + (size_t)(i * 4 + w) * 512 + l * 8);
        }
        __syncthreads();

        bf16x8 af[4], bfr[4];
#pragma unroll
        for (int m = 0; m < 4; ++m)
            af[m] = *reinterpret_cast<const bf16x8*>(&Ahi[wr * 64 + m * 16 + c][g * 8]);
#pragma unroll
        for (int n = 0; n < 4; ++n)
            bfr[n] = *reinterpret_cast<const bf16x8*>(&Bs[wc * 64 + n * 16 + c][g * 8]);
#pragma unroll
        for (int m = 0; m < 4; ++m)
#pragma unroll
            for (int n = 0; n < 4; ++n)
                acc[m][n] = __builtin_amdgcn_mfma_f32_16x16x32_bf16(af[m], bfr[n], acc[m][n], 0, 0, 0);
    }

#pragma unroll
    for (int m = 0; m < 4; ++m)
#pragma unroll
        for (int n = 0; n < 4; ++n)
#pragma unroll
            for (int r = 0; r < 4; ++r) {
                int row = row0 + wr * 64 + m * 16 + g * 4 + r;
                int col = col0 + wc * 64 + n * 16 + c;
                stC(&C[(size_t)row * N + col], acc[m][n][r]);
            }
}

// ---------------- swapped 32x32 differential attention, STREAM-SPLIT waves ----------------
// R23 attn = R19/R21 exactly (proven 126.5-127.3us, VGPR 96, (256,2)).
// Probed and rejected: pairing(R15), 128-row tile(R17), KVBLK=32(R20), 3-blk bound(R22).
__global__ __launch_bounds__(256, 2) void attn_mfma(
        const bf16* __restrict__ cp,
        const float* __restrict__ lq1, const float* __restrict__ lk1,
        const float* __restrict__ lq2, const float* __restrict__ lk2,
        bf16* __restrict__ merged) {
    __shared__ ushort_t K1s[2][64][64];
    __shared__ ushort_t K2s[2][64][64];
    __shared__ ushort_t Vt[DV][VSTR];

    const int t = threadIdx.x;
    const int w = t >> 6, l = t & 63;
    const int lane = l & 31, h2 = l >> 5;
    const int qgrp = w >> 1, strm = w & 1;

    const int bid = blockIdx.x;
    const int qt  = 31 - (bid >> 5);          // qt-descending
    const int bh  = bid & 31;
    const int h   = bh & (NH - 1), b = bh >> 4;
    const int q0  = qt * 64;
    const int qw0 = q0 + 32 * qgrp;
    const int qg  = qw0 + lane;
    const int ntiles = qt + 1;

    float lam;
    {
        float s1 = lq1[h * DH + l] * lk1[h * DH + l];
        float s2 = lq2[h * DH + l] * lk2[h * DH + l];
#pragma unroll
        for (int m = 32; m >= 1; m >>= 1) {
            s1 += __shfl_xor(s1, m, 64);
            s2 += __shfl_xor(s2, m, 64);
        }
        lam = __expf(s1) - __expf(s2) + LAM0;
    }

    // Q fragments for OWN stream only (B-operand; k = 16*kk + 8*h2 + j)
    bf16x8 qf[4];
    {
        const int QO = strm ? Q2O : Q1O;
        size_t qrow = (size_t)(b * SS + qg) * PJW + h * DH;
#pragma unroll
        for (int kk = 0; kk < 4; ++kk)
            qf[kk] = *reinterpret_cast<const bf16x8*>(&cp[qrow + QO + 16 * kk + 8 * h2]);
    }

    // ---- staging (hoisted pointers) ----
    const size_t TSTEP = (size_t)64 * PJW;
    const int u0 = t, u1 = 256 + t;
    const int r0u = u0 >> 3, jj0 = (u0 & 7) ^ (r0u & 7);
    const int r1u = u1 >> 3, jj1 = (u1 & 7) ^ (r1u & 7);
    const bf16* k1p0 = cp + (size_t)(b * SS + r0u) * PJW + h * DH + jj0 * 8 + K1O;
    const bf16* k1p1 = cp + (size_t)(b * SS + r1u) * PJW + h * DH + jj1 * 8 + K1O;
    const bf16* k2p0 = k1p0 + (K2O - K1O);
    const bf16* k2p1 = k1p1 + (K2O - K1O);
    auto stageK = [&](int buf) {
        bf16* d1 = (bf16*)&K1s[buf][0][0];
        bf16* d2 = (bf16*)&K2s[buf][0][0];
        gload_lds16(k1p0, d1 + u0 * 8);
        gload_lds16(k1p1, d1 + u1 * 8);
        gload_lds16(k2p0, d2 + u0 * 8);
        gload_lds16(k2p1, d2 + u1 * 8);
        k1p0 += TSTEP; k1p1 += TSTEP; k2p0 += TSTEP; k2p1 += TSTEP;
    };
    uint4 va[4];
    const int vk4 = (t & 15) * 4, vc8 = (t >> 4) * 8;
    const bf16* vp0 = cp + (size_t)(b * SS + vk4 + 0) * PJW + VO + h * DV + vc8;
    const bf16* vp1 = cp + (size_t)(b * SS + vk4 + 1) * PJW + VO + h * DV + vc8;
    const bf16* vp2 = cp + (size_t)(b * SS + vk4 + 2) * PJW + VO + h * DV + vc8;
    const bf16* vp3 = cp + (size_t)(b * SS + vk4 + 3) * PJW + VO + h * DV + vc8;
    auto loadV = [&]() {
        va[0] = *reinterpret_cast<const uint4*>(vp0);
        va[1] = *reinterpret_cast<const uint4*>(vp1);
        va[2] = *reinterpret_cast<const uint4*>(vp2);
        va[3] = *reinterpret_cast<const uint4*>(vp3);
        vp0 += TSTEP; vp1 += TSTEP; vp2 += TSTEP; vp3 += TSTEP;
    };

    f32x16 acc[4];
    const f32x16 fz16 = {0.f,0.f,0.f,0.f,0.f,0.f,0.f,0.f,0.f,0.f,0.f,0.f,0.f,0.f,0.f,0.f};
#pragma unroll
    for (int i = 0; i < 4; ++i) acc[i] = fz16;
    float mm = -1e30f, lsum = 0.f;

    // prologue
    stageK(0);
    loadV();

    for (int kt = 0; kt < ntiles; ++kt) {
        const int cur = kt & 1;
        const int k0 = kt * 64;
        const bool diag = (kt + 1 == ntiles);
        const bool skipHi = diag && (qgrp == 0);   // keys 32..63 fully masked

        __syncthreads();                    // A: prev reads done; K DMA + va landed
        if (kt + 1 < ntiles) stageK(cur ^ 1);
        {   // Vt transpose-pack via v_perm (1 op per packed word)
            const uint_t* w0 = reinterpret_cast<const uint_t*>(&va[0]);
            const uint_t* w1 = reinterpret_cast<const uint_t*>(&va[1]);
            const uint_t* w2 = reinterpret_cast<const uint_t*>(&va[2]);
            const uint_t* w3 = reinterpret_cast<const uint_t*>(&va[3]);
#pragma unroll
            for (int j = 0; j < 8; ++j) {
                const int jw = j >> 1;
                const uint_t sel = (j & 1) ? PSEL_HI : PSEL_LO;
                uint2 pk;
                pk.x = __builtin_amdgcn_perm(w1[jw], w0[jw], sel);
                pk.y = __builtin_amdgcn_perm(w3[jw], w2[jw], sel);
                *reinterpret_cast<uint2*>(&Vt[vc8 + j][vk4]) = pk;
            }
        }
        if (kt + 1 < ntiles) loadV();

        // B: Vt + K visible; prefetches stay in flight
        asm volatile("s_waitcnt lgkmcnt(0)" ::: "memory");
        __builtin_amdgcn_sched_barrier(0);
        __builtin_amdgcn_s_barrier();
        __builtin_amdgcn_sched_barrier(0);

        const ushort_t (*Ks)[64] = strm ? K2s[cur] : K1s[cur];

        // ---- QK^T (own stream): lane owns one q, 32 keys in-register ----
        f32x16 sA = fz16, sB = fz16;
        __builtin_amdgcn_s_setprio(1);
#pragma unroll
        for (int kk = 0; kk < 4; ++kk) {
            const int un = ((2 * kk + h2) ^ (lane & 7)) * 8;
            bf16x8 a0 = *reinterpret_cast<const bf16x8*>(&Ks[lane][un]);
            sA = __builtin_amdgcn_mfma_f32_32x32x16_bf16(a0, qf[kk], sA, 0, 0, 0);
        }
        if (!skipHi) {
#pragma unroll
            for (int kk = 0; kk < 4; ++kk) {
                const int un = ((2 * kk + h2) ^ (lane & 7)) * 8;
                bf16x8 a1 = *reinterpret_cast<const bf16x8*>(&Ks[32 + lane][un]);
                sB = __builtin_amdgcn_mfma_f32_32x32x16_bf16(a1, qf[kk], sB, 0, 0, 0);
            }
        }
        __builtin_amdgcn_s_setprio(0);

        float sv[32];
#pragma unroll
        for (int i = 0; i < 16; ++i) { sv[i] = sA[i]; sv[16 + i] = sB[i]; }
        if (diag) {
#pragma unroll
            for (int sb = 0; sb < 2; ++sb)
#pragma unroll
                for (int r = 0; r < 16; ++r) {
                    int key = k0 + 32 * sb + (r & 3) + 8 * (r >> 2) + 4 * h2;
                    if (key > qg) sv[16 * sb + r] = -1e30f;
                }
        }
        // max3-structured tree max over 32 + one cross-half exchange
        float tA[11];
#pragma unroll
        for (int i = 0; i < 10; ++i)
            tA[i] = fmaxf(fmaxf(sv[3 * i], sv[3 * i + 1]), sv[3 * i + 2]);
        tA[10] = fmaxf(sv[30], sv[31]);
        float u0m = fmaxf(fmaxf(tA[0], tA[1]), tA[2]);
        float u1m = fmaxf(fmaxf(tA[3], tA[4]), tA[5]);
        float u2m = fmaxf(fmaxf(tA[6], tA[7]), tA[8]);
        float u3m = fmaxf(tA[9], tA[10]);
        float mt = fmaxf(fmaxf(fmaxf(u0m, u1m), u2m), u3m);
        mt = fmaxf(mt, __shfl_xor(mt, 32, 64));

        float f = 1.f;
        if (!__all(mt - mm <= 8.f)) {
            float mn = fmaxf(mm, mt);
            f = exp2f(mm - mn); mm = mn;
#pragma unroll
            for (int vb = 0; vb < 4; ++vb)
#pragma unroll
                for (int i = 0; i < 16; ++i) acc[vb][i] *= f;
        }

        float rs = 0.f;
        uint2 pa[8];
#pragma unroll
        for (int kc = 0; kc < 4; ++kc) {
            const int base = 4 * kc;          // keys subblock 0
            float p0 = exp2f(sv[base + 0] - mm);
            float p1 = exp2f(sv[base + 1] - mm);
            float p2 = exp2f(sv[base + 2] - mm);
            float p3 = exp2f(sv[base + 3] - mm);
            rs += (p0 + p1) + (p2 + p3);
            bf16 b0 = __float2bfloat16(p0), b1 = __float2bfloat16(p1);
            bf16 b2 = __float2bfloat16(p2), b3 = __float2bfloat16(p3);
            pa[kc].x = (uint_t)(*reinterpret_cast<ushort_t*>(&b0))
                     | ((uint_t)(*reinterpret_cast<ushort_t*>(&b1)) << 16);
            pa[kc].y = (uint_t)(*reinterpret_cast<ushort_t*>(&b2))
                     | ((uint_t)(*reinterpret_cast<ushort_t*>(&b3)) << 16);
        }
        if (!skipHi) {
#pragma unroll
            for (int kc = 4; kc < 8; ++kc) {
                const int base = 16 + 4 * (kc & 3);   // keys subblock 1
                float p0 = exp2f(sv[base + 0] - mm);
                float p1 = exp2f(sv[base + 1] - mm);
                float p2 = exp2f(sv[base + 2] - mm);
                float p3 = exp2f(sv[base + 3] - mm);
                rs += (p0 + p1) + (p2 + p3);
                bf16 b0 = __float2bfloat16(p0), b1 = __float2bfloat16(p1);
                bf16 b2 = __float2bfloat16(p2), b3 = __float2bfloat16(p3);
                pa[kc].x = (uint_t)(*reinterpret_cast<ushort_t*>(&b0))
                         | ((uint_t)(*reinterpret_cast<ushort_t*>(&b1)) << 16);
                pa[kc].y = (uint_t)(*reinterpret_cast<ushort_t*>(&b2))
                         | ((uint_t)(*reinterpret_cast<ushort_t*>(&b3)) << 16);
            }
        }
        lsum = lsum * f + rs;

        __builtin_amdgcn_s_setprio(1);
#pragma unroll
        for (int vb = 0; vb < 4; ++vb)
#pragma unroll
            for (int kc = 0; kc < 4; ++kc) {
                uint2 vf = *reinterpret_cast<const uint2*>(&Vt[32 * vb + lane][8 * kc + 4 * h2]);
                acc[vb] = mfma_pv(vf, pa[kc], acc[vb]);
            }
        if (!skipHi) {
#pragma unroll
            for (int vb = 0; vb < 4; ++vb)
#pragma unroll
                for (int kc = 4; kc < 8; ++kc) {
                    uint2 vf = *reinterpret_cast<const uint2*>(&Vt[32 * vb + lane][8 * kc + 4 * h2]);
                    acc[vb] = mfma_pv(vf, pa[kc], acc[vb]);
                }
        }
        __builtin_amdgcn_s_setprio(0);
    }

    // ---- epilogue: stream exchange + combine + LN + store ----
    lsum += __shfl_xor(lsum, 32, 64);
    const float rl = __builtin_amdgcn_rcpf(lsum);

    float (*ex)[33] = reinterpret_cast<float(*)[33]>(
        qgrp ? (void*)&K2s[0][0][0] : (void*)&K1s[0][0][0]);

    __syncthreads();                        // all loop-phase LDS reads done
#pragma unroll
    for (int half = 0; half < 2; ++half) {
        if (strm) {
#pragma unroll
            for (int vv = 0; vv < 2; ++vv)
#pragma unroll
                for (int i = 0; i < 16; ++i)
                    ex[l][16 * vv + i] = acc[2 * half + vv][i] * rl;
        }
        __syncthreads();
        if (!strm) {
#pragma unroll
            for (int vv = 0; vv < 2; ++vv)
#pragma unroll
                for (int i = 0; i < 16; ++i)
                    acc[2 * half + vv][i] =
                        acc[2 * half + vv][i] * rl - lam * ex[l][16 * vv + i];
        }
        __syncthreads();
    }

    if (!strm) {
        float sum = 0.f;
#pragma unroll
        for (int vb = 0; vb < 4; ++vb)
#pragma unroll
            for (int i = 0; i < 16; ++i) sum += acc[vb][i];
        sum += __shfl_xor(sum, 32, 64);
        const float mu = sum * (1.f / 128.f);
        float var = 0.f;
#pragma unroll
        for (int vb = 0; vb < 4; ++vb)
#pragma unroll
            for (int i = 0; i < 16; ++i) {
                float d = acc[vb][i] - mu;
                var += d * d;
            }
        var += __shfl_xor(var, 32, 64);
        const float scl = rsqrtf(var * (1.f / 128.f) + LN_EPS) * (1.f - LAM0);

        const size_t orow = (size_t)(b * SS + qg) * (2 * EE) + h * DV;
#pragma unroll
        for (int vb = 0; vb < 4; ++vb)
#pragma unroll
            for (int rq = 0; rq < 4; ++rq) {
                bf16 o0 = __float2bfloat16((acc[vb][4 * rq + 0] - mu) * scl);
                bf16 o1 = __float2bfloat16((acc[vb][4 * rq + 1] - mu) * scl);
                bf16 o2 = __float2bfloat16((acc[vb][4 * rq + 2] - mu) * scl);
                bf16 o3 = __float2bfloat16((acc[vb][4 * rq + 3] - mu) * scl);
                uint2 pk;
                pk.x = (uint_t)(*reinterpret_cast<ushort_t*>(&o0))
                     | ((uint_t)(*reinterpret_cast<ushort_t*>(&o1)) << 16);
                pk.y = (uint_t)(*reinterpret_cast<ushort_t*>(&o2))
                     | ((uint_t)(*reinterpret_cast<ushort_t*>(&o3)) << 16);
                *reinterpret_cast<uint2*>(&merged[orow + 32 * vb + 8 * rq + 4 * h2]) = pk;
            }
    }
}

// ---------------- launch ----------------
extern "C" void kernel_launch(void* const* d_in, const int* in_sizes, int n_in,
                              void* d_out, int out_size, void* d_ws, size_t ws_size,
                              hipStream_t stream) {
    (void)in_sizes; (void)n_in; (void)out_size; (void)ws_size;
    const float* x   = (const float*)d_in[0];
    const float* Wq1 = (const float*)d_in[1];
    const float* Wq2 = (const float*)d_in[2];
    const float* Wk1 = (const float*)d_in[3];
    const float* Wk2 = (const float*)d_in[4];
    const float* Wv  = (const float*)d_in[5];
    const float* Wo  = (const float*)d_in[6];
    const float* lq1 = (const float*)d_in[7];
    const float* lk1 = (const float*)d_in[8];
    const float* lq2 = (const float*)d_in[9];
    const float* lk2 = (const float*)d_in[10];
    float* out = (float*)d_out;

    char* ws = (char*)d_ws;
    const size_t MB = 1ull << 20;
    bf16* wcT = (bf16*)(ws);                 // [0,12M)
    bf16* cpj = (bf16*)(ws + 16 * MB);       // [16M,64M)
    bf16* mg  = (bf16*)(ws);                 // [0,16M)  (after proj, wcT dead)
    bf16* woT = (bf16*)(ws + 16 * MB);       // [16M,20M) (after attn, cpj dead)
    bf16* xb  = (bf16*)d_out;                // x-bf16 scratch (overwritten by final GEMM)

    dim3 blk(256);
    prep<<<dim3(64, 32, 6), blk, 0, stream>>>(Wq1, Wq2, Wk1, Wk2, Wv, x, wcT, xb);
    mgemm<bf16><<<dim3((6144 / 128) * (4096 / 128)), blk, 0, stream>>>(
        xb, wcT, cpj, 4096, 6144, 1024);
    attn_mfma<<<dim3(NB * NH * (SS / 64)), blk, 0, stream>>>(
        cpj, lq1, lk1, lq2, lk2, mg);
    transp<<<dim3(32, 64), blk, 0, stream>>>(Wo, woT, 2048, 1024, 2048, 0, 1.0f);
    mgemm<float><<<dim3((1024 / 128) * (4096 / 128)), blk, 0, stream>>>(
        mg, woT, out, 4096, 1024, 2048);
}